// Round 4
// baseline (320.378 us; speedup 1.0000x reference)
//
#include <hip/hip_runtime.h>

#define HH 512
#define WW 512
#define TILE 32
#define HALO 5
#define LT (TILE + 2 * HALO) /* 42 */
#define STR 43               /* LDS row stride in float4 */
#define PI_F 3.14159265358979323846f

// All lookup tables constexpr at file scope: folded accesses (constant index
// after unroll) leave no per-thread stack object -> no scratch (R3 lesson).
__device__ constexpr int DIMIN[11] = {5, 2, 1, 1, 1, 0, 1, 1, 1, 2, 5};
__device__ constexpr int DIMAX[11] = {5, 8, 9, 9, 9, 10, 9, 9, 9, 8, 5};
// sorted position of each valid d2 (wm = rank > SP[d2]); d2 asc == dist asc
__device__ constexpr int SP[26] = {0, 1, 2, -1, 3, 4, -1, -1, 5, 6, 7, -1, -1,
                                   8, -1, -1, 9, 10, 11, -1, 12, -1, -1, -1, -1, 13};
__device__ constexpr int AA[14] = {0, 0, 1, 0, 1, 2, 0, 1, 2, 0, 1, 3, 2, 0};
__device__ constexpr int CC[14] = {0, 1, 1, 2, 2, 2, 3, 3, 3, 4, 4, 3, 4, 5};

// Depth-aware scatter (splat) bokeh as gather.
// out[b,c,y,x] = sum_disk [r(src)>=dist] g(src) rgb(src,c) / sum_disk [r(src)>=dist] g(src)
// Per source pixel: rank = #{sorted dists <= r} (exact f32 compares against the
// input diskernel floats) packed into g's low 4 mantissa bits -> inner loop is
// ONE ds_read_b128 per source row, shared by a 1x4 output strip.
// CRITICAL: every loop below has LITERAL bounds + fold-after-unroll guards
// (LLVM unrolls innermost loops first; runtime bounds there -> scratch, R3).
__global__ __launch_bounds__(256, 4) void Scatter_Rendering_87101936763449_kernel(
    const float* __restrict__ x, const float* __restrict__ lens,
    const float* __restrict__ dk, float* __restrict__ out) {
    __shared__ float4 sg[LT * STR]; // (s0, s1, s2, g|rank)

    const int b  = blockIdx.z;
    const int bx = blockIdx.x * TILE;
    const int by = blockIdx.y * TILE;
    const int t  = threadIdx.x;

    const float le = lens[b];
    const float* xb = x + (size_t)b * 4 * HH * WW;

    // 14 distinct dist values ascending, from the INPUT diskernel (exact floats
    // the reference compares against). Static indices -> registers.
    float dsort[14];
#pragma unroll
    for (int k = 0; k < 14; ++k) dsort[k] = dk[(5 + AA[k]) * 11 + (5 + CC[k])];

    // Stage 42x42 halo'd tile: one float4 per source pixel.
    for (int i = t; i < LT * LT; i += 256) {
        int ly = i / LT, lx = i - ly * LT;
        int gy = by + ly - HALO; gy = gy < 0 ? 0 : (gy > HH - 1 ? HH - 1 : gy);
        int gx = bx + lx - HALO; gx = gx < 0 ? 0 : (gx > WW - 1 ? WW - 1 : gx);
        int gi = gy * WW + gx;
        float d = xb[3 * HH * WW + gi];
        float r = fminf(fabsf(d) * le, (float)HALO);
        float g = 1.0f / (PI_F * r * r + 1.0f);
        int rank = 0;
#pragma unroll
        for (int k = 0; k < 14; ++k) rank += (r >= dsort[k]) ? 1 : 0; // exact coverage
        // rank in [0,14] -> low 4 mantissa bits of g (rel. perturbation <= 2^-19)
        float gm = __uint_as_float((__float_as_uint(g) & ~15u) | (unsigned)rank);
        sg[ly * STR + lx] = make_float4(xb[gi] * g, xb[HH * WW + gi] * g,
                                        xb[2 * HH * WW + gi] * g, gm);
    }

    __syncthreads();

    const int tx   = t & 31;
    const int yloc = (t >> 5) * 4; // this thread owns output rows yloc..yloc+3

    float acc[4][4] = {{0.f}}; // [p][{r,g,b,den}], static indices after unroll

#pragma unroll
    for (int dj = 0; dj < 11; ++dj) {
        const int lo = DIMIN[dj], hi = DIMAX[dj]; // constant after dj unroll
#pragma unroll
        for (int k = 0; k < 14; ++k) {            // LITERAL bounds
            if (k < lo || k > hi + 3) continue;   // folds once dj is unrolled
            // rolling window: source row k serves pixel p at di = k - p
            const float4 v = sg[(yloc + k) * STR + (tx + dj)];
            const int rk = (int)(__float_as_uint(v.w) & 15u);
#pragma unroll
            for (int p = 0; p < 4; ++p) {
                const int di = k - p;
                if (di < lo || di > hi) continue; // folds after unroll
                const int d2 = (di - 5) * (di - 5) + (dj - 5) * (dj - 5);
                const float wm = (rk > SP[d2]) ? 1.0f : 0.0f;
                acc[p][0] = fmaf(wm, v.x, acc[p][0]);
                acc[p][1] = fmaf(wm, v.y, acc[p][1]);
                acc[p][2] = fmaf(wm, v.z, acc[p][2]);
                acc[p][3] = fmaf(wm, v.w, acc[p][3]);
            }
        }
    }

#pragma unroll
    for (int p = 0; p < 4; ++p) {
        const float inv = 1.0f / acc[p][3];
        const size_t o = (size_t)b * 3 * HH * WW + (size_t)(by + yloc + p) * WW + (bx + tx);
        out[o]               = acc[p][0] * inv;
        out[o + HH * WW]     = acc[p][1] * inv;
        out[o + 2 * HH * WW] = acc[p][2] * inv;
    }
}

extern "C" void kernel_launch(void* const* d_in, const int* in_sizes, int n_in,
                              void* d_out, int out_size, void* d_ws, size_t ws_size,
                              hipStream_t stream) {
    const float* x    = (const float*)d_in[0]; // (4,4,512,512)
    const float* lens = (const float*)d_in[1]; // (4,1)
    const float* dk   = (const float*)d_in[2]; // (11,11)
    float* out = (float*)d_out;                // (4,3,512,512)

    dim3 grid(WW / TILE, HH / TILE, 4);        // 16x16x4 = 1024 blocks (4/CU)
    dim3 block(256);
    hipLaunchKernelGGL(Scatter_Rendering_87101936763449_kernel, grid, block, 0, stream,
                       x, lens, dk, out);
}

// Round 6
// 87.204 us; speedup vs baseline: 3.6739x; 3.6739x over previous
//
#include <hip/hip_runtime.h>

#define HH 512
#define WW 512
#define TILE 32
#define HALO 5
#define LT (TILE + 2 * HALO) /* 42 */
#define STR 43               /* LDS row stride in float4 */
#define PI_F 3.14159265358979323846f

// ---- compile-time disk geometry (constexpr functions: usable in if constexpr,
// no memory object exists at runtime). R3/R4 lesson: the optimizer did NOT
// fully unroll the loop nest, so guards/table-indices stayed runtime and acc
// went to scratch (428MB fetch / 405MB write of spill traffic). Templates make
// the unroll a language guarantee instead of an optimizer outcome.
constexpr int dimin(int dj) {
    return (dj == 0 || dj == 10) ? 5 : (dj == 1 || dj == 9) ? 2 : (dj == 5) ? 0 : 1;
}
constexpr int dimax(int dj) { return 10 - dimin(dj); }
// sorted position of d2 among the 14 distinct values {0,1,2,4,5,8,9,10,13,16,17,18,20,25}
constexpr int spv(int d2) {
    return d2 == 0 ? 0 : d2 == 1 ? 1 : d2 == 2 ? 2 : d2 == 4 ? 3 : d2 == 5 ? 4 :
           d2 == 8 ? 5 : d2 == 9 ? 6 : d2 == 10 ? 7 : d2 == 13 ? 8 : d2 == 16 ? 9 :
           d2 == 17 ? 10 : d2 == 18 ? 11 : d2 == 20 ? 12 : 13;
}

// pixel P (output row yloc+P) consumes source row K at di = K-P, column DJ.
template <int DJ, int K, int P>
__device__ __forceinline__ void pstep(const float4& v, int rk, float (&acc)[4][4]) {
    constexpr int di = K - P;
    if constexpr (di >= dimin(DJ) && di <= dimax(DJ)) {
        constexpr int d2 = (di - 5) * (di - 5) + (DJ - 5) * (DJ - 5);
        const float wm = (rk > spv(d2)) ? 1.0f : 0.0f; // rank>s <=> r >= dist[s], exact
        acc[P][0] = fmaf(wm, v.x, acc[P][0]);
        acc[P][1] = fmaf(wm, v.y, acc[P][1]);
        acc[P][2] = fmaf(wm, v.z, acc[P][2]);
        acc[P][3] = fmaf(wm, v.w, acc[P][3]);
    }
}

// one ds_read_b128 at compile-time offset K*STR+DJ, shared by 4 output pixels.
template <int DJ, int K>
__device__ __forceinline__ void kstep(const float4* __restrict__ sgp, float (&acc)[4][4]) {
    if constexpr (K >= dimin(DJ) && K <= dimax(DJ) + 3) {
        const float4 v = sgp[K * STR + DJ];
        const int rk = (int)(__float_as_uint(v.w) & 15u);
        pstep<DJ, K, 0>(v, rk, acc);
        pstep<DJ, K, 1>(v, rk, acc);
        pstep<DJ, K, 2>(v, rk, acc);
        pstep<DJ, K, 3>(v, rk, acc);
    }
}

template <int DJ>
__device__ __forceinline__ void colstep(const float4* __restrict__ sgp, float (&acc)[4][4]) {
    kstep<DJ, 0>(sgp, acc);  kstep<DJ, 1>(sgp, acc);  kstep<DJ, 2>(sgp, acc);
    kstep<DJ, 3>(sgp, acc);  kstep<DJ, 4>(sgp, acc);  kstep<DJ, 5>(sgp, acc);
    kstep<DJ, 6>(sgp, acc);  kstep<DJ, 7>(sgp, acc);  kstep<DJ, 8>(sgp, acc);
    kstep<DJ, 9>(sgp, acc);  kstep<DJ, 10>(sgp, acc); kstep<DJ, 11>(sgp, acc);
    kstep<DJ, 12>(sgp, acc); kstep<DJ, 13>(sgp, acc);
}

// Depth-aware scatter (splat) bokeh as gather.
// out[b,c,y,x] = sum_disk [r(src)>=dist] g(src) rgb(src,c) / sum_disk [r(src)>=dist] g(src)
// Per source pixel: rank = #{sorted dists <= r} (exact f32 compares against the
// input diskernel floats) packed into g's low 4 mantissa bits -> inner loop is
// ONE ds_read_b128 per source row, shared by a 1x4 output strip.
__global__ __launch_bounds__(256, 4) void Scatter_Rendering_87101936763449_kernel(
    const float* __restrict__ x, const float* __restrict__ lens,
    const float* __restrict__ dk, float* __restrict__ out) {
    __shared__ float4 sg[LT * STR]; // (s0, s1, s2, g|rank)

    const int b  = blockIdx.z;
    const int bx = blockIdx.x * TILE;
    const int by = blockIdx.y * TILE;
    const int t  = threadIdx.x;

    const float le = lens[b];
    const float* xb = x + (size_t)b * 4 * HH * WW;

    // 14 distinct dist values ascending, straight from the INPUT diskernel
    // (exact floats the reference compares with). Representative (a,c) per d2.
    float dsort[14];
    {
        constexpr int AA[14] = {0, 0, 1, 0, 1, 2, 0, 1, 2, 0, 1, 3, 2, 0};
        constexpr int CC[14] = {0, 1, 1, 2, 2, 2, 3, 3, 3, 4, 4, 3, 4, 5};
#pragma unroll
        for (int k = 0; k < 14; ++k) dsort[k] = dk[(5 + AA[k]) * 11 + (5 + CC[k])];
    }

    // Stage 42x42 halo'd tile: one float4 per source pixel.
    for (int i = t; i < LT * LT; i += 256) {
        int ly = i / LT, lx = i - ly * LT;
        int gy = by + ly - HALO; gy = gy < 0 ? 0 : (gy > HH - 1 ? HH - 1 : gy);
        int gx = bx + lx - HALO; gx = gx < 0 ? 0 : (gx > WW - 1 ? WW - 1 : gx);
        int gi = gy * WW + gx;
        float d = xb[3 * HH * WW + gi];
        float r = fminf(fabsf(d) * le, (float)HALO);
        float g = 1.0f / (PI_F * r * r + 1.0f);
        int rank = 0;
#pragma unroll
        for (int k = 0; k < 14; ++k) rank += (r >= dsort[k]) ? 1 : 0; // exact coverage
        // rank in [0,14] -> low 4 mantissa bits of g (rel. perturbation <= 2^-19)
        float gm = __uint_as_float((__float_as_uint(g) & ~15u) | (unsigned)rank);
        sg[ly * STR + lx] = make_float4(xb[gi] * g, xb[HH * WW + gi] * g,
                                        xb[2 * HH * WW + gi] * g, gm);
    }

    __syncthreads();

    const int tx   = t & 31;
    const int yloc = (t >> 5) * 4; // this thread owns output rows yloc..yloc+3

    float acc[4][4] = {{0.f}};
    const float4* sgp = &sg[yloc * STR + tx]; // all further offsets compile-time

    colstep<0>(sgp, acc); colstep<1>(sgp, acc); colstep<2>(sgp, acc);
    colstep<3>(sgp, acc); colstep<4>(sgp, acc); colstep<5>(sgp, acc);
    colstep<6>(sgp, acc); colstep<7>(sgp, acc); colstep<8>(sgp, acc);
    colstep<9>(sgp, acc); colstep<10>(sgp, acc);

#pragma unroll
    for (int p = 0; p < 4; ++p) {
        const float inv = 1.0f / acc[p][3];
        const size_t o = (size_t)b * 3 * HH * WW + (size_t)(by + yloc + p) * WW + (bx + tx);
        out[o]               = acc[p][0] * inv;
        out[o + HH * WW]     = acc[p][1] * inv;
        out[o + 2 * HH * WW] = acc[p][2] * inv;
    }
}

extern "C" void kernel_launch(void* const* d_in, const int* in_sizes, int n_in,
                              void* d_out, int out_size, void* d_ws, size_t ws_size,
                              hipStream_t stream) {
    const float* x    = (const float*)d_in[0]; // (4,4,512,512)
    const float* lens = (const float*)d_in[1]; // (4,1)
    const float* dk   = (const float*)d_in[2]; // (11,11)
    float* out = (float*)d_out;                // (4,3,512,512)

    dim3 grid(WW / TILE, HH / TILE, 4);        // 16x16x4 = 1024 blocks (4/CU)
    dim3 block(256);
    hipLaunchKernelGGL(Scatter_Rendering_87101936763449_kernel, grid, block, 0, stream,
                       x, lens, dk, out);
}